// Round 1
// baseline (1002.045 us; speedup 1.0000x reference)
//
#include <hip/hip_runtime.h>
#include <hip/hip_bf16.h>

// Problem constants
#define BB 2
#define HH 128
#define WW 128
#define CC 256
#define DD 64
#define PP 18
#define NN 16384            // H*W
#define ROWS 32768          // B*N
#define EPSF 1e-5f

// ---------------------------------------------------------------------------
// Kernel 1: Xp = X + pos_enc (broadcast over batch). float4 vectorized.
// total floats = ROWS*CC = 8388608 -> 2097152 float4
__global__ __launch_bounds__(256) void k_xp(const float4* __restrict__ X,
                                            const float4* __restrict__ pe,
                                            float4* __restrict__ Xp) {
    int i = blockIdx.x * 256 + threadIdx.x;          // 0 .. 2097151
    float4 a = X[i];
    float4 b = pe[i & 1048575];                      // N*C/4 = 1048576 (pow2)
    Xp[i] = make_float4(a.x + b.x, a.y + b.y, a.z + b.z, a.w + b.w);
}

// ---------------------------------------------------------------------------
// Kernel 2: generic tiled fp32 GEMM  C[M,Nw] = A[M,K] @ W[K,Nw] + bias
// tile 64x64, K-step 16, 256 threads, 4x4 per-thread microtile.
__global__ __launch_bounds__(256) void k_gemm(const float* __restrict__ A,
                                              const float* __restrict__ W,
                                              const float* __restrict__ bias,
                                              float* __restrict__ C,
                                              int M, int K, int Nw) {
    __shared__ float As[64][17];   // padded leading dim
    __shared__ float Ws[16][64];

    const int t  = threadIdx.x;
    const int m0 = blockIdx.x * 64;
    const int n0 = blockIdx.y * 64;
    const int tx = t & 15;         // col group
    const int ty = t >> 4;         // row group

    float acc[4][4];
#pragma unroll
    for (int i = 0; i < 4; ++i)
#pragma unroll
        for (int j = 0; j < 4; ++j) acc[i][j] = 0.f;

    const int idx = t * 4;
    const int am = idx >> 4, ak = idx & 15;   // A-tile coords (64 x 16)
    const int wk = idx >> 6, wn = idx & 63;   // W-tile coords (16 x 64)

    for (int k0 = 0; k0 < K; k0 += 16) {
        float4 av = *(const float4*)&A[(long)(m0 + am) * K + k0 + ak];
        As[am][ak + 0] = av.x;
        As[am][ak + 1] = av.y;
        As[am][ak + 2] = av.z;
        As[am][ak + 3] = av.w;
        float4 wv = *(const float4*)&W[(long)(k0 + wk) * Nw + n0 + wn];
        *(float4*)&Ws[wk][wn] = wv;
        __syncthreads();
#pragma unroll
        for (int kk = 0; kk < 16; ++kk) {
            float a[4], w[4];
#pragma unroll
            for (int i = 0; i < 4; ++i) a[i] = As[ty * 4 + i][kk];
#pragma unroll
            for (int j = 0; j < 4; ++j) w[j] = Ws[kk][tx * 4 + j];
#pragma unroll
            for (int i = 0; i < 4; ++i)
#pragma unroll
                for (int j = 0; j < 4; ++j) acc[i][j] += a[i] * w[j];
        }
        __syncthreads();
    }

#pragma unroll
    for (int i = 0; i < 4; ++i) {
        int r = m0 + ty * 4 + i;
        float4 o;
        o.x = acc[i][0] + bias[n0 + tx * 4 + 0];
        o.y = acc[i][1] + bias[n0 + tx * 4 + 1];
        o.z = acc[i][2] + bias[n0 + tx * 4 + 2];
        o.w = acc[i][3] + bias[n0 + tx * 4 + 3];
        *(float4*)&C[(long)r * Nw + n0 + tx * 4] = o;
    }
}

// ---------------------------------------------------------------------------
// Kernel 3: gather-attention. One wave (64 lanes) per token; lane = dim d.
// 4 tokens per 256-thread block.
__global__ __launch_bounds__(256) void k_attn(const float* __restrict__ Q,
                                              const float* __restrict__ K,
                                              const float* __restrict__ V,
                                              const int* __restrict__ sel,
                                              float* __restrict__ ctx,
                                              float* __restrict__ attn_out) {
    const int wave  = threadIdx.x >> 6;
    const int lane  = threadIdx.x & 63;
    const int token = blockIdx.x * 4 + wave;          // 0..32767
    const int b     = token >> 14;                    // N = 16384
    const float q   = Q[token * DD + lane];

    int   idx[PP];
    float sc[PP];
    const int* selp = sel + (long)token * PP;
#pragma unroll
    for (int p = 0; p < PP; ++p) idx[p] = selp[p];

#pragma unroll
    for (int p = 0; p < PP; ++p) {
        float v = q * K[(((b << 14) + idx[p]) << 6) + lane];
#pragma unroll
        for (int o = 32; o > 0; o >>= 1) v += __shfl_xor(v, o);
        sc[p] = v * 0.125f;                           // / sqrt(64)
    }

    float mx = sc[0];
#pragma unroll
    for (int p = 1; p < PP; ++p) mx = fmaxf(mx, sc[p]);
    float e[PP];
    float s = 0.f;
#pragma unroll
    for (int p = 0; p < PP; ++p) { e[p] = expf(sc[p] - mx); s += e[p]; }
    const float inv = 1.f / s;

    // write attention weights (lanes 0..17, coalesced)
    float aval = 0.f;
#pragma unroll
    for (int p = 0; p < PP; ++p) aval = (lane == p) ? e[p] * inv : aval;
    if (lane < PP) attn_out[(long)token * PP + lane] = aval;

    // ctx = sum_p attn[p] * V[idx_p]
    float cv = 0.f;
#pragma unroll
    for (int p = 0; p < PP; ++p)
        cv += (e[p] * inv) * V[(((b << 14) + idx[p]) << 6) + lane];
    ctx[token * DD + lane] = cv;
}

// ---------------------------------------------------------------------------
// Kernel 4: out = ctx @ Wo + bo ; Xn = LN(Xp + out) * g1 + be1 (in-place on Xp)
// Wo (64x256 = 64KB) staged in LDS; 16 rows per block.
__global__ __launch_bounds__(256) void k_projln(const float* __restrict__ ctx,
                                                const float* __restrict__ Wo,
                                                const float* __restrict__ bo,
                                                const float* __restrict__ g1,
                                                const float* __restrict__ be1,
                                                float* __restrict__ XpXn) {
    __shared__ float wo[DD * CC];       // 64 KB
    __shared__ float cs[16][DD];        // 4 KB
    __shared__ float red[8];
    const int t = threadIdx.x;
    const int row0 = blockIdx.x * 16;

    // stage Wo
    for (int i = t * 4; i < DD * CC; i += 1024)
        *(float4*)&wo[i] = *(const float4*)&Wo[i];
    // stage ctx rows (16*64 = 1024 floats)
    {
        int i = t * 4;
        int r = i >> 6, k = i & 63;
        *(float4*)&cs[r][k] = *(const float4*)&ctx[(long)(row0 + r) * DD + k];
    }
    __syncthreads();

    const int lane = t & 63, wid = t >> 6;
    for (int r = 0; r < 16; ++r) {
        float acc = 0.f;
#pragma unroll
        for (int k = 0; k < DD; ++k) acc += cs[r][k] * wo[k * CC + t];
        const long gi = (long)(row0 + r) * CC + t;
        float x = XpXn[gi] + acc + bo[t];

        float s = x, q = x * x;
#pragma unroll
        for (int o = 32; o > 0; o >>= 1) { s += __shfl_xor(s, o); q += __shfl_xor(q, o); }
        if (lane == 0) { red[wid] = s; red[4 + wid] = q; }
        __syncthreads();
        if (t == 0) {
            float S = red[0] + red[1] + red[2] + red[3];
            float Qq = red[4] + red[5] + red[6] + red[7];
            float mu = S * (1.f / CC);
            float var = Qq * (1.f / CC) - mu * mu;
            red[0] = mu; red[1] = rsqrtf(var + EPSF);
        }
        __syncthreads();
        float mu = red[0], rs = red[1];
        XpXn[gi] = (x - mu) * rs * g1[t] + be1[t];
        __syncthreads();
    }
}

// ---------------------------------------------------------------------------
// Kernel 5: fused FFN + LN2.
// 8 rows per block; hidden (1024) processed in 8 chunks of 128 through LDS.
__global__ __launch_bounds__(256) void k_ffn(const float* __restrict__ Xn,
                                             const float* __restrict__ W1,
                                             const float* __restrict__ b1,
                                             const float* __restrict__ W2,
                                             const float* __restrict__ b2,
                                             const float* __restrict__ g2,
                                             const float* __restrict__ be2,
                                             float* __restrict__ out) {
    __shared__ float xs[8][CC];        // 8 KB
    __shared__ float hs[8][128];       // 4 KB
    __shared__ float rp[4][8][2];
    __shared__ float mrs[8][2];

    const int t = threadIdx.x;
    const int row0 = blockIdx.x * 8;

    // stage Xn rows (8*256 = 2048 floats)
    for (int i = t * 4; i < 8 * CC; i += 1024) {
        int r = i >> 8, c = i & 255;
        *(float4*)&xs[r][c] = *(const float4*)&Xn[(long)(row0 + r) * CC + c];
    }
    __syncthreads();

    float acc[8];
#pragma unroll
    for (int r = 0; r < 8; ++r) acc[r] = 0.f;

    const int hl = t & 127;
    const int rbase = t >> 7;          // 0 or 1

    for (int ch = 0; ch < 8; ++ch) {
        const int h0 = ch * 128;
        float ha[4] = {0.f, 0.f, 0.f, 0.f};
        for (int k = 0; k < CC; ++k) {
            float w = W1[(long)k * 1024 + h0 + hl];
#pragma unroll
            for (int j = 0; j < 4; ++j) ha[j] += xs[rbase + 2 * j][k] * w;
        }
        __syncthreads();               // previous hs fully consumed
#pragma unroll
        for (int j = 0; j < 4; ++j)
            hs[rbase + 2 * j][hl] = fmaxf(ha[j] + b1[h0 + hl], 0.f);
        __syncthreads();
        for (int h = 0; h < 128; ++h) {
            float w2 = W2[(long)(h0 + h) * CC + t];
#pragma unroll
            for (int r = 0; r < 8; ++r) acc[r] += hs[r][h] * w2;
        }
    }

    // residual + LN2
    float xr[8];
#pragma unroll
    for (int r = 0; r < 8; ++r) xr[r] = xs[r][t] + acc[r] + b2[t];

    const int lane = t & 63, wid = t >> 6;
#pragma unroll
    for (int r = 0; r < 8; ++r) {
        float s = xr[r], q = xr[r] * xr[r];
#pragma unroll
        for (int o = 32; o > 0; o >>= 1) { s += __shfl_xor(s, o); q += __shfl_xor(q, o); }
        if (lane == 0) { rp[wid][r][0] = s; rp[wid][r][1] = q; }
    }
    __syncthreads();
    if (t < 8) {
        float S = 0.f, Qq = 0.f;
#pragma unroll
        for (int w = 0; w < 4; ++w) { S += rp[w][t][0]; Qq += rp[w][t][1]; }
        float mu = S * (1.f / CC);
        float var = Qq * (1.f / CC) - mu * mu;
        mrs[t][0] = mu;
        mrs[t][1] = rsqrtf(var + EPSF);
    }
    __syncthreads();
#pragma unroll
    for (int r = 0; r < 8; ++r)
        out[(long)(row0 + r) * CC + t] =
            (xr[r] - mrs[r][0]) * mrs[r][1] * g2[t] + be2[t];
}

// ---------------------------------------------------------------------------
extern "C" void kernel_launch(void* const* d_in, const int* in_sizes, int n_in,
                              void* d_out, int out_size, void* d_ws, size_t ws_size,
                              hipStream_t stream) {
    const float* X   = (const float*)d_in[0];
    const int*   sel = (const int*)d_in[1];
    // d_in[2] = topk (unused, ==1)
    const float* pe  = (const float*)d_in[3];
    const float* Wq  = (const float*)d_in[4];
    const float* bq  = (const float*)d_in[5];
    const float* Wk  = (const float*)d_in[6];
    const float* bk  = (const float*)d_in[7];
    const float* Wv  = (const float*)d_in[8];
    const float* bv  = (const float*)d_in[9];
    const float* Wo  = (const float*)d_in[10];
    const float* bo  = (const float*)d_in[11];
    const float* W1  = (const float*)d_in[12];
    const float* b1  = (const float*)d_in[13];
    const float* W2  = (const float*)d_in[14];
    const float* b2  = (const float*)d_in[15];
    const float* g1  = (const float*)d_in[16];
    const float* be1 = (const float*)d_in[17];
    const float* g2  = (const float*)d_in[18];
    const float* be2 = (const float*)d_in[19];

    float* out = (float*)d_out;
    float* ws  = (float*)d_ws;

    float* Xp   = ws;                        // 8388608 floats (becomes Xn in-place)
    float* Qb   = ws + 8388608;              // 2097152
    float* Kb   = Qb + 2097152;              // 2097152
    float* Vb   = Kb + 2097152;              // 2097152
    float* ctxb = Vb + 2097152;              // 2097152
    float* attn_out = out + (long)ROWS * CC; // second tuple element

    k_xp<<<8192, 256, 0, stream>>>((const float4*)X, (const float4*)pe, (float4*)Xp);

    k_gemm<<<dim3(ROWS / 64, 1), 256, 0, stream>>>(Xp, Wq, bq, Qb, ROWS, CC, DD);
    k_gemm<<<dim3(ROWS / 64, 1), 256, 0, stream>>>(Xp, Wk, bk, Kb, ROWS, CC, DD);
    k_gemm<<<dim3(ROWS / 64, 1), 256, 0, stream>>>(Xp, Wv, bv, Vb, ROWS, CC, DD);

    k_attn<<<ROWS / 4, 256, 0, stream>>>(Qb, Kb, Vb, sel, ctxb, attn_out);

    k_projln<<<ROWS / 16, 256, 0, stream>>>(ctxb, Wo, bo, g1, be1, Xp);

    k_ffn<<<ROWS / 8, 256, 0, stream>>>(Xp, W1, b1, W2, b2, g2, be2, out);
}

// Round 2
// 323.109 us; speedup vs baseline: 3.1013x; 3.1013x over previous
//
#include <hip/hip_runtime.h>
#include <hip/hip_bf16.h>

// Problem constants
#define BB 2
#define HH 128
#define WW 128
#define CC 256
#define DD 64
#define PP 18
#define NN 16384            // H*W
#define ROWS 32768          // B*N
#define EPSF 1e-5f

typedef __attribute__((ext_vector_type(8))) short bf16x8;
typedef __attribute__((ext_vector_type(4))) float f32x4;

// ---------------------------------------------------------------------------
// Kernel 1: Xp = X + pos_enc (broadcast over batch). float4 vectorized.
__global__ __launch_bounds__(256) void k_xp(const float4* __restrict__ X,
                                            const float4* __restrict__ pe,
                                            float4* __restrict__ Xp) {
    int i = blockIdx.x * 256 + threadIdx.x;          // 0 .. 2097151
    float4 a = X[i];
    float4 b = pe[i & 1048575];                      // N*C/4 = 1048576 (pow2)
    Xp[i] = make_float4(a.x + b.x, a.y + b.y, a.z + b.z, a.w + b.w);
}

// ---------------------------------------------------------------------------
// Weight transpose + fp32->bf16: out[n*K + k] = bf16(in[k*N + n])
__global__ __launch_bounds__(256) void k_w_t(const float* __restrict__ in,
                                             __hip_bfloat16* __restrict__ out,
                                             int K, int N) {
    int i = blockIdx.x * 256 + threadIdx.x;
    if (i >= K * N) return;
    int n = i / K, k = i - n * K;
    out[i] = __float2bfloat16(in[k * N + n]);
}

// ---------------------------------------------------------------------------
// Kernel 2: generic tiled fp32 GEMM  C[M,Nw] = A[M,K] @ W[K,Nw] + bias
__global__ __launch_bounds__(256) void k_gemm(const float* __restrict__ A,
                                              const float* __restrict__ W,
                                              const float* __restrict__ bias,
                                              float* __restrict__ C,
                                              int M, int K, int Nw) {
    __shared__ float As[64][17];
    __shared__ float Ws[16][64];

    const int t  = threadIdx.x;
    const int m0 = blockIdx.x * 64;
    const int n0 = blockIdx.y * 64;
    const int tx = t & 15;
    const int ty = t >> 4;

    float acc[4][4];
#pragma unroll
    for (int i = 0; i < 4; ++i)
#pragma unroll
        for (int j = 0; j < 4; ++j) acc[i][j] = 0.f;

    const int idx = t * 4;
    const int am = idx >> 4, ak = idx & 15;
    const int wk = idx >> 6, wn = idx & 63;

    for (int k0 = 0; k0 < K; k0 += 16) {
        float4 av = *(const float4*)&A[(long)(m0 + am) * K + k0 + ak];
        As[am][ak + 0] = av.x;
        As[am][ak + 1] = av.y;
        As[am][ak + 2] = av.z;
        As[am][ak + 3] = av.w;
        float4 wv = *(const float4*)&W[(long)(k0 + wk) * Nw + n0 + wn];
        *(float4*)&Ws[wk][wn] = wv;
        __syncthreads();
#pragma unroll
        for (int kk = 0; kk < 16; ++kk) {
            float a[4], w[4];
#pragma unroll
            for (int i = 0; i < 4; ++i) a[i] = As[ty * 4 + i][kk];
#pragma unroll
            for (int j = 0; j < 4; ++j) w[j] = Ws[kk][tx * 4 + j];
#pragma unroll
            for (int i = 0; i < 4; ++i)
#pragma unroll
                for (int j = 0; j < 4; ++j) acc[i][j] += a[i] * w[j];
        }
        __syncthreads();
    }

#pragma unroll
    for (int i = 0; i < 4; ++i) {
        int r = m0 + ty * 4 + i;
        float4 o;
        o.x = acc[i][0] + bias[n0 + tx * 4 + 0];
        o.y = acc[i][1] + bias[n0 + tx * 4 + 1];
        o.z = acc[i][2] + bias[n0 + tx * 4 + 2];
        o.w = acc[i][3] + bias[n0 + tx * 4 + 3];
        *(float4*)&C[(long)r * Nw + n0 + tx * 4] = o;
    }
}

// ---------------------------------------------------------------------------
// Kernel 3: gather-attention. One wave per token; lane = dim d.
__global__ __launch_bounds__(256) void k_attn(const float* __restrict__ Q,
                                              const float* __restrict__ K,
                                              const float* __restrict__ V,
                                              const int* __restrict__ sel,
                                              float* __restrict__ ctx,
                                              float* __restrict__ attn_out) {
    const int wave  = threadIdx.x >> 6;
    const int lane  = threadIdx.x & 63;
    const int token = blockIdx.x * 4 + wave;
    const int b     = token >> 14;
    const float q   = Q[token * DD + lane];

    int   idx[PP];
    float sc[PP];
    const int* selp = sel + (long)token * PP;
#pragma unroll
    for (int p = 0; p < PP; ++p) idx[p] = selp[p];

#pragma unroll
    for (int p = 0; p < PP; ++p) {
        float v = q * K[(((b << 14) + idx[p]) << 6) + lane];
#pragma unroll
        for (int o = 32; o > 0; o >>= 1) v += __shfl_xor(v, o);
        sc[p] = v * 0.125f;
    }

    float mx = sc[0];
#pragma unroll
    for (int p = 1; p < PP; ++p) mx = fmaxf(mx, sc[p]);
    float e[PP];
    float s = 0.f;
#pragma unroll
    for (int p = 0; p < PP; ++p) { e[p] = expf(sc[p] - mx); s += e[p]; }
    const float inv = 1.f / s;

    float aval = 0.f;
#pragma unroll
    for (int p = 0; p < PP; ++p) aval = (lane == p) ? e[p] * inv : aval;
    if (lane < PP) attn_out[(long)token * PP + lane] = aval;

    float cv = 0.f;
#pragma unroll
    for (int p = 0; p < PP; ++p)
        cv += (e[p] * inv) * V[(((b << 14) + idx[p]) << 6) + lane];
    ctx[token * DD + lane] = cv;
}

// ---------------------------------------------------------------------------
// Kernel 4: out = ctx @ Wo + bo ; Xn = LN(Xp + out) -> bf16 Xnb
__global__ __launch_bounds__(256) void k_projln(const float* __restrict__ ctx,
                                                const float* __restrict__ Wo,
                                                const float* __restrict__ bo,
                                                const float* __restrict__ g1,
                                                const float* __restrict__ be1,
                                                const float* __restrict__ Xp,
                                                __hip_bfloat16* __restrict__ Xnb) {
    __shared__ float wo[DD * CC];       // 64 KB
    __shared__ float cs[16][DD];
    __shared__ float red[8];
    const int t = threadIdx.x;
    const int row0 = blockIdx.x * 16;

    for (int i = t * 4; i < DD * CC; i += 1024)
        *(float4*)&wo[i] = *(const float4*)&Wo[i];
    {
        int i = t * 4;
        int r = i >> 6, k = i & 63;
        *(float4*)&cs[r][k] = *(const float4*)&ctx[(long)(row0 + r) * DD + k];
    }
    __syncthreads();

    const int lane = t & 63, wid = t >> 6;
    for (int r = 0; r < 16; ++r) {
        float acc = 0.f;
#pragma unroll
        for (int k = 0; k < DD; ++k) acc += cs[r][k] * wo[k * CC + t];
        const long gi = (long)(row0 + r) * CC + t;
        float x = Xp[gi] + acc + bo[t];

        float s = x, q = x * x;
#pragma unroll
        for (int o = 32; o > 0; o >>= 1) { s += __shfl_xor(s, o); q += __shfl_xor(q, o); }
        if (lane == 0) { red[wid] = s; red[4 + wid] = q; }
        __syncthreads();
        if (t == 0) {
            float S = red[0] + red[1] + red[2] + red[3];
            float Qq = red[4] + red[5] + red[6] + red[7];
            float mu = S * (1.f / CC);
            float var = Qq * (1.f / CC) - mu * mu;
            red[0] = mu; red[1] = rsqrtf(var + EPSF);
        }
        __syncthreads();
        float mu = red[0], rs = red[1];
        Xnb[gi] = __float2bfloat16((x - mu) * rs * g1[t] + be1[t]);
        __syncthreads();
    }
}

// ---------------------------------------------------------------------------
// Kernel 5: fused FFN + LN2 with bf16 MFMA.
// Block = 64 rows, 256 threads (4 waves). 8 hidden chunks of 128.
// Wave w: phase1 computes H cols [w*32, w*32+32); phase2 computes O cols
// [w*64, w*64+64). LDS tiles XOR-swizzled (byte ^= (row&7)<<4).
__global__ __launch_bounds__(256) void k_ffn_mfma(
    const __hip_bfloat16* __restrict__ Xn,   // [32768][256]
    const __hip_bfloat16* __restrict__ W1T,  // [1024][256]  (n-major)
    const float* __restrict__ b1,
    const __hip_bfloat16* __restrict__ W2T,  // [256][1024]  (n-major)
    const float* __restrict__ b2,
    const float* __restrict__ g2,
    const float* __restrict__ be2,
    float* __restrict__ out) {
    __shared__ short Xs[64 * 256];      // 32 KB, swizzled
    __shared__ short Hs[64 * 128];      // 16 KB, swizzled
    __shared__ float red[4][64][2];     // 2 KB
    __shared__ float mrs[64][2];

    const int t   = threadIdx.x;
    const int w   = t >> 6;
    const int l   = t & 63;
    const int l15 = l & 15;
    const int lh  = l >> 4;             // 0..3
    const int row0 = blockIdx.x * 64;

    // ---- stage X tile (bf16, swizzled) ----
    {
        const char* src = (const char*)(Xn + (long)row0 * 256);
        for (int j = t; j < 2048; j += 256) {     // 16B chunks
            int r  = j >> 5;
            int db = (r << 9) + ((j & 31) << 4);
            db ^= (r & 7) << 4;
            *(bf16x8*)((char*)Xs + db) = *(const bf16x8*)(src + ((long)j << 4));
        }
    }
    __syncthreads();

    f32x4 oacc[4][4];
#pragma unroll
    for (int i = 0; i < 4; ++i)
#pragma unroll
        for (int j = 0; j < 4; ++j) oacc[i][j] = (f32x4)(0.f);

    for (int c = 0; c < 8; ++c) {
        // ---- phase 1: hacc = X @ W1c ----
        f32x4 hacc[4][2];
#pragma unroll
        for (int i = 0; i < 4; ++i)
#pragma unroll
            for (int j = 0; j < 2; ++j) hacc[i][j] = (f32x4)(0.f);

        for (int ks = 0; ks < 8; ++ks) {
            bf16x8 a[4];
#pragma unroll
            for (int ri = 0; ri < 4; ++ri) {
                int r  = ri * 16 + l15;
                int db = (r << 9) + ks * 64 + lh * 16;
                db ^= (r & 7) << 4;
                a[ri] = *(const bf16x8*)((const char*)Xs + db);
            }
#pragma unroll
            for (int ci = 0; ci < 2; ++ci) {
                int n = c * 128 + w * 32 + ci * 16 + l15;
                bf16x8 b = *(const bf16x8*)(W1T + (long)n * 256 + ks * 32 + lh * 8);
#pragma unroll
                for (int ri = 0; ri < 4; ++ri)
                    hacc[ri][ci] = __builtin_amdgcn_mfma_f32_16x16x32_bf16(
                        a[ri], b, hacc[ri][ci], 0, 0, 0);
            }
        }
        __syncthreads();                 // previous Hs fully consumed
        // ---- write H = relu(hacc + b1) to LDS (bf16, swizzled) ----
#pragma unroll
        for (int ci = 0; ci < 2; ++ci) {
            int n = c * 128 + w * 32 + ci * 16 + l15;
            float bias = b1[n];
            int colb = (w * 32 + ci * 16 + l15) * 2;
#pragma unroll
            for (int ri = 0; ri < 4; ++ri)
#pragma unroll
                for (int rg = 0; rg < 4; ++rg) {
                    int r  = ri * 16 + lh * 4 + rg;
                    int db = (r << 8) + colb;
                    db ^= (r & 7) << 4;
                    float v = fmaxf(hacc[ri][ci][rg] + bias, 0.f);
                    *(__hip_bfloat16*)((char*)Hs + db) = __float2bfloat16(v);
                }
        }
        __syncthreads();
        // ---- phase 2: oacc += H @ W2c ----
        for (int ks = 0; ks < 4; ++ks) {
            bf16x8 a[4];
#pragma unroll
            for (int ri = 0; ri < 4; ++ri) {
                int r  = ri * 16 + l15;
                int db = (r << 8) + ks * 64 + lh * 16;
                db ^= (r & 7) << 4;
                a[ri] = *(const bf16x8*)((const char*)Hs + db);
            }
#pragma unroll
            for (int ci = 0; ci < 4; ++ci) {
                int n = w * 64 + ci * 16 + l15;
                long kk = (long)c * 128 + ks * 32 + lh * 8;
                bf16x8 b = *(const bf16x8*)(W2T + (long)n * 1024 + kk);
#pragma unroll
                for (int ri = 0; ri < 4; ++ri)
                    oacc[ri][ci] = __builtin_amdgcn_mfma_f32_16x16x32_bf16(
                        a[ri], b, oacc[ri][ci], 0, 0, 0);
            }
        }
    }

    // ---- epilogue: residual + LN2 ----
    float b2c[4], g2c[4], be2c[4];
#pragma unroll
    for (int ci = 0; ci < 4; ++ci) {
        int n = w * 64 + ci * 16 + l15;
        b2c[ci] = b2[n]; g2c[ci] = g2[n]; be2c[ci] = be2[n];
    }
#pragma unroll
    for (int ri = 0; ri < 4; ++ri)
#pragma unroll
        for (int rg = 0; rg < 4; ++rg) {
            int r = ri * 16 + lh * 4 + rg;
            float s = 0.f, q = 0.f;
#pragma unroll
            for (int ci = 0; ci < 4; ++ci) {
                int db = (r << 9) + (w * 64 + ci * 16 + l15) * 2;
                db ^= (r & 7) << 4;
                float xn = __bfloat162float(*(__hip_bfloat16*)((char*)Xs + db));
                float v = oacc[ri][ci][rg] + xn + b2c[ci];
                oacc[ri][ci][rg] = v;
                s += v; q += v * v;
            }
#pragma unroll
            for (int o = 8; o > 0; o >>= 1) {
                s += __shfl_xor(s, o); q += __shfl_xor(q, o);
            }
            if (l15 == 0) { red[w][r][0] = s; red[w][r][1] = q; }
        }
    __syncthreads();
    if (t < 64) {
        float S = 0.f, Q = 0.f;
#pragma unroll
        for (int ww = 0; ww < 4; ++ww) { S += red[ww][t][0]; Q += red[ww][t][1]; }
        float mu = S * (1.f / CC);
        float var = Q * (1.f / CC) - mu * mu;
        mrs[t][0] = mu; mrs[t][1] = rsqrtf(var + EPSF);
    }
    __syncthreads();
#pragma unroll
    for (int ri = 0; ri < 4; ++ri)
#pragma unroll
        for (int rg = 0; rg < 4; ++rg) {
            int r = ri * 16 + lh * 4 + rg;
            float mu = mrs[r][0], rs = mrs[r][1];
#pragma unroll
            for (int ci = 0; ci < 4; ++ci) {
                int col = w * 64 + ci * 16 + l15;
                out[(long)(row0 + r) * CC + col] =
                    (oacc[ri][ci][rg] - mu) * rs * g2c[ci] + be2c[ci];
            }
        }
}

// ---------------------------------------------------------------------------
extern "C" void kernel_launch(void* const* d_in, const int* in_sizes, int n_in,
                              void* d_out, int out_size, void* d_ws, size_t ws_size,
                              hipStream_t stream) {
    const float* X   = (const float*)d_in[0];
    const int*   sel = (const int*)d_in[1];
    const float* pe  = (const float*)d_in[3];
    const float* Wq  = (const float*)d_in[4];
    const float* bq  = (const float*)d_in[5];
    const float* Wk  = (const float*)d_in[6];
    const float* bk  = (const float*)d_in[7];
    const float* Wv  = (const float*)d_in[8];
    const float* bv  = (const float*)d_in[9];
    const float* Wo  = (const float*)d_in[10];
    const float* bo  = (const float*)d_in[11];
    const float* W1  = (const float*)d_in[12];
    const float* b1  = (const float*)d_in[13];
    const float* W2  = (const float*)d_in[14];
    const float* b2  = (const float*)d_in[15];
    const float* g1  = (const float*)d_in[16];
    const float* be1 = (const float*)d_in[17];
    const float* g2  = (const float*)d_in[18];
    const float* be2 = (const float*)d_in[19];

    float* out = (float*)d_out;
    float* ws  = (float*)d_ws;

    float* Xp   = ws;                        // 8388608 floats
    float* Qb   = ws + 8388608;              // 2097152
    float* Kb   = Qb + 2097152;
    float* Vb   = Kb + 2097152;
    float* ctxb = Vb + 2097152;              // ends at 16777216
    __hip_bfloat16* W1T = (__hip_bfloat16*)(ws + 16777216);       // 262144 bf16
    __hip_bfloat16* W2T = W1T + 262144;                           // 262144 bf16
    __hip_bfloat16* Xnb = (__hip_bfloat16*)Qb;  // aliases Q+K (dead after attn)
    float* attn_out = out + (long)ROWS * CC;

    k_xp<<<8192, 256, 0, stream>>>((const float4*)X, (const float4*)pe, (float4*)Xp);

    k_w_t<<<1024, 256, 0, stream>>>(W1, W1T, CC, 1024);      // W1T[1024][256]
    k_w_t<<<1024, 256, 0, stream>>>(W2, W2T, 1024, CC);      // W2T[256][1024]

    k_gemm<<<dim3(ROWS / 64, 1), 256, 0, stream>>>(Xp, Wq, bq, Qb, ROWS, CC, DD);
    k_gemm<<<dim3(ROWS / 64, 1), 256, 0, stream>>>(Xp, Wk, bk, Kb, ROWS, CC, DD);
    k_gemm<<<dim3(ROWS / 64, 1), 256, 0, stream>>>(Xp, Wv, bv, Vb, ROWS, CC, DD);

    k_attn<<<ROWS / 4, 256, 0, stream>>>(Qb, Kb, Vb, sel, ctxb, attn_out);

    k_projln<<<ROWS / 16, 256, 0, stream>>>(ctxb, Wo, bo, g1, be1, Xp, Xnb);

    k_ffn_mfma<<<ROWS / 64, 256, 0, stream>>>(Xnb, W1T, b1, W2T, b2, g2, be2, out);
}

// Round 3
// 189.299 us; speedup vs baseline: 5.2935x; 1.7069x over previous
//
#include <hip/hip_runtime.h>
#include <hip/hip_bf16.h>

#define CC 256
#define DD 64
#define PP 18
#define ROWS 32768
#define EPSF 1e-5f

typedef __attribute__((ext_vector_type(8))) short bf16x8;
typedef __attribute__((ext_vector_type(4))) short s16x4;
typedef __attribute__((ext_vector_type(4))) float f32x4;

// ---------------------------------------------------------------------------
// Pack fp32 weight W[K][N] (k-major) into MFMA B-fragment order, bf16:
// out[((nt*(K/32) + ks)*64 + lane)*8 + e] = W[ks*32 + (lane>>4)*8 + e][nt*16 + (lane&15)]
__global__ __launch_bounds__(256) void k_pack(const float* __restrict__ W,
                                              __hip_bfloat16* __restrict__ out,
                                              int K, int N) {
    int i = blockIdx.x * 256 + threadIdx.x;
    if (i >= K * N) return;
    int e = i & 7, l = (i >> 3) & 63, rest = i >> 9;
    int KS = K >> 5;
    int ks = rest % KS, nt = rest / KS;
    int row = ks * 32 + (l >> 4) * 8 + e;
    int col = nt * 16 + (l & 15);
    out[i] = __float2bfloat16(W[(long)row * N + col]);
}

// ---------------------------------------------------------------------------
// Fused QKV: stage Xp=X+pe (bf16, swizzled LDS; also write Xpb), then
// Q/K/V = Xp @ W{q,k,v} via MFMA. 64 rows/block, 4 waves; wave w owns rows
// w*16..w*16+16, all 192 output cols.
__global__ __launch_bounds__(256) void k_qkv(
    const float4* __restrict__ X4, const float4* __restrict__ pe4,
    const __hip_bfloat16* __restrict__ WqP, const __hip_bfloat16* __restrict__ WkP,
    const __hip_bfloat16* __restrict__ WvP,
    const float* __restrict__ bq, const float* __restrict__ bk,
    const float* __restrict__ bv,
    __hip_bfloat16* __restrict__ Xpb,
    __hip_bfloat16* __restrict__ Qb, __hip_bfloat16* __restrict__ Kb,
    __hip_bfloat16* __restrict__ Vb) {
    __shared__ short Xs[64 * 256];      // 32 KB, swizzled
    const int t = threadIdx.x, w = t >> 6, l = t & 63;
    const int l15 = l & 15, lh = l >> 4;
    const int row0 = blockIdx.x * 64;

    for (int j = t; j < 4096; j += 256) {          // 64 rows x 64 float4
        int r = j >> 6, c4 = j & 63;
        long g = row0 + r;
        float4 a = X4[(g << 6) + c4];
        float4 p = pe4[(long)((g & 16383) << 6) + c4];
        union { s16x4 v; __hip_bfloat16 h[4]; } u;
        u.h[0] = __float2bfloat16(a.x + p.x);
        u.h[1] = __float2bfloat16(a.y + p.y);
        u.h[2] = __float2bfloat16(a.z + p.z);
        u.h[3] = __float2bfloat16(a.w + p.w);
        int db = (r << 9) + (c4 << 3);
        db ^= (r & 7) << 4;
        *(s16x4*)((char*)Xs + db) = u.v;
        *(s16x4*)((char*)Xpb + (g << 9) + (c4 << 3)) = u.v;
    }
    __syncthreads();

    f32x4 acc[12];
#pragma unroll
    for (int i = 0; i < 12; ++i) acc[i] = (f32x4)(0.f);

    const int arow = w * 16 + l15;
#pragma unroll
    for (int ks = 0; ks < 8; ++ks) {
        int db = (arow << 9) + ks * 64 + lh * 16;
        db ^= (arow & 7) << 4;
        bf16x8 a = *(const bf16x8*)((const char*)Xs + db);
#pragma unroll
        for (int nt = 0; nt < 4; ++nt) {
            bf16x8 b = *(const bf16x8*)(WqP + (long)(((nt * 8 + ks) << 6) + l) * 8);
            acc[nt] = __builtin_amdgcn_mfma_f32_16x16x32_bf16(a, b, acc[nt], 0, 0, 0);
        }
#pragma unroll
        for (int nt = 0; nt < 4; ++nt) {
            bf16x8 b = *(const bf16x8*)(WkP + (long)(((nt * 8 + ks) << 6) + l) * 8);
            acc[4 + nt] = __builtin_amdgcn_mfma_f32_16x16x32_bf16(a, b, acc[4 + nt], 0, 0, 0);
        }
#pragma unroll
        for (int nt = 0; nt < 4; ++nt) {
            bf16x8 b = *(const bf16x8*)(WvP + (long)(((nt * 8 + ks) << 6) + l) * 8);
            acc[8 + nt] = __builtin_amdgcn_mfma_f32_16x16x32_bf16(a, b, acc[8 + nt], 0, 0, 0);
        }
    }

    const int grow0 = row0 + w * 16 + lh * 4;
#pragma unroll
    for (int nt = 0; nt < 4; ++nt) {
        float bqv = bq[nt * 16 + l15];
        float bkv = bk[nt * 16 + l15];
        float bvv = bv[nt * 16 + l15];
#pragma unroll
        for (int rg = 0; rg < 4; ++rg) {
            long ro = (long)(grow0 + rg) * DD + nt * 16 + l15;
            Qb[ro] = __float2bfloat16(acc[nt][rg] + bqv);
            Kb[ro] = __float2bfloat16(acc[4 + nt][rg] + bkv);
            Vb[ro] = __float2bfloat16(acc[8 + nt][rg] + bvv);
        }
    }
}

// ---------------------------------------------------------------------------
// Gather-attention, bf16 K/V. One wave per token.
__global__ __launch_bounds__(256) void k_attn(const __hip_bfloat16* __restrict__ Q,
                                              const __hip_bfloat16* __restrict__ K,
                                              const __hip_bfloat16* __restrict__ V,
                                              const int* __restrict__ sel,
                                              __hip_bfloat16* __restrict__ ctx,
                                              float* __restrict__ attn_out) {
    const int wave  = threadIdx.x >> 6;
    const int lane  = threadIdx.x & 63;
    const int token = blockIdx.x * 4 + wave;
    const int b     = token >> 14;
    const float q   = __bfloat162float(Q[token * DD + lane]);

    int   idx[PP];
    float sc[PP];
    const int* selp = sel + (long)token * PP;
#pragma unroll
    for (int p = 0; p < PP; ++p) idx[p] = selp[p];

#pragma unroll
    for (int p = 0; p < PP; ++p) {
        float v = q * __bfloat162float(K[(((b << 14) + idx[p]) << 6) + lane]);
#pragma unroll
        for (int o = 32; o > 0; o >>= 1) v += __shfl_xor(v, o);
        sc[p] = v * 0.125f;
    }

    float mx = sc[0];
#pragma unroll
    for (int p = 1; p < PP; ++p) mx = fmaxf(mx, sc[p]);
    float e[PP];
    float s = 0.f;
#pragma unroll
    for (int p = 0; p < PP; ++p) { e[p] = expf(sc[p] - mx); s += e[p]; }
    const float inv = 1.f / s;

    float aval = 0.f;
#pragma unroll
    for (int p = 0; p < PP; ++p) aval = (lane == p) ? e[p] * inv : aval;
    if (lane < PP) attn_out[(long)token * PP + lane] = aval;

    float cv = 0.f;
#pragma unroll
    for (int p = 0; p < PP; ++p)
        cv += (e[p] * inv) * __bfloat162float(V[(((b << 14) + idx[p]) << 6) + lane]);
    ctx[token * DD + lane] = __float2bfloat16(cv);
}

// ---------------------------------------------------------------------------
// proj + LN1: Xn = LN(Xpb + ctx@Wo + bo)*g1 + be1 -> bf16.
// 64 rows/block, 4 waves; wave w owns rows w*16..16, all 256 cols. Within-wave LN.
__global__ __launch_bounds__(256) void k_projln(
    const __hip_bfloat16* __restrict__ ctx, const __hip_bfloat16* __restrict__ WoP,
    const float* __restrict__ bo, const float* __restrict__ g1,
    const float* __restrict__ be1,
    const __hip_bfloat16* __restrict__ Xpb, __hip_bfloat16* __restrict__ Xnb) {
    __shared__ short Cs[64 * 64];       // 8 KB, swizzled
    const int t = threadIdx.x, w = t >> 6, l = t & 63;
    const int l15 = l & 15, lh = l >> 4;
    const int row0 = blockIdx.x * 64;

    for (int j = t; j < 512; j += 256) {           // 64 rows x 8 x 16B
        int r = j >> 3, ch = j & 7;
        int db = (r << 7) + (ch << 4);
        db ^= (r & 7) << 4;
        *(bf16x8*)((char*)Cs + db) = *(const bf16x8*)(ctx + (long)(row0 + r) * DD + ch * 8);
    }
    __syncthreads();

    f32x4 acc[16];
#pragma unroll
    for (int i = 0; i < 16; ++i) acc[i] = (f32x4)(0.f);

    const int arow = w * 16 + l15;
#pragma unroll
    for (int ks = 0; ks < 2; ++ks) {
        int db = (arow << 7) + ks * 64 + lh * 16;
        db ^= (arow & 7) << 4;
        bf16x8 a = *(const bf16x8*)((const char*)Cs + db);
#pragma unroll
        for (int nt = 0; nt < 16; ++nt) {
            bf16x8 b = *(const bf16x8*)(WoP + (long)(((nt * 2 + ks) << 6) + l) * 8);
            acc[nt] = __builtin_amdgcn_mfma_f32_16x16x32_bf16(a, b, acc[nt], 0, 0, 0);
        }
    }

    float bov[16], g1v[16], be1v[16];
#pragma unroll
    for (int nt = 0; nt < 16; ++nt) {
        bov[nt] = bo[nt * 16 + l15];
        g1v[nt] = g1[nt * 16 + l15];
        be1v[nt] = be1[nt * 16 + l15];
    }

    const int grow0 = row0 + w * 16 + lh * 4;
#pragma unroll
    for (int rg = 0; rg < 4; ++rg) {
        long gr = grow0 + rg;
        float x[16];
        float s = 0.f, q = 0.f;
#pragma unroll
        for (int nt = 0; nt < 16; ++nt) {
            float v = acc[nt][rg] + bov[nt] +
                      __bfloat162float(Xpb[gr * CC + nt * 16 + l15]);
            x[nt] = v; s += v; q += v * v;
        }
#pragma unroll
        for (int o = 8; o > 0; o >>= 1) { s += __shfl_xor(s, o); q += __shfl_xor(q, o); }
        float mu = s * (1.f / CC);
        float var = q * (1.f / CC) - mu * mu;
        float rs = rsqrtf(var + EPSF);
#pragma unroll
        for (int nt = 0; nt < 16; ++nt)
            Xnb[gr * CC + nt * 16 + l15] =
                __float2bfloat16((x[nt] - mu) * rs * g1v[nt] + be1v[nt]);
    }
}

// ---------------------------------------------------------------------------
// Fused FFN + LN2. 64 rows/block, 4 waves, 8 hidden chunks of 128.
// Double-buffered H (1 barrier/chunk), packed coalesced weight fragments.
__global__ __launch_bounds__(256) void k_ffn_mfma(
    const __hip_bfloat16* __restrict__ Xn,
    const __hip_bfloat16* __restrict__ W1P, const float* __restrict__ b1,
    const __hip_bfloat16* __restrict__ W2P, const float* __restrict__ b2,
    const float* __restrict__ g2, const float* __restrict__ be2,
    float* __restrict__ out) {
    __shared__ short Xs[64 * 256];      // 32 KB
    __shared__ short Hs[2][64 * 128];   // 32 KB
    __shared__ float red[4][64][2];
    __shared__ float mrs[64][2];

    const int t = threadIdx.x, w = t >> 6, l = t & 63;
    const int l15 = l & 15, lh = l >> 4;
    const int row0 = blockIdx.x * 64;

    {
        const char* src = (const char*)(Xn + (long)row0 * CC);
        for (int j = t; j < 2048; j += 256) {
            int r = j >> 5;
            int db = (r << 9) + ((j & 31) << 4);
            db ^= (r & 7) << 4;
            *(bf16x8*)((char*)Xs + db) = *(const bf16x8*)(src + ((long)j << 4));
        }
    }
    __syncthreads();

    f32x4 oacc[4][4];
#pragma unroll
    for (int i = 0; i < 4; ++i)
#pragma unroll
        for (int j = 0; j < 4; ++j) oacc[i][j] = (f32x4)(0.f);

    for (int c = 0; c < 8; ++c) {
        // -- phase 1 B fragments (coalesced packed) --
        bf16x8 b1r[2][8];
#pragma unroll
        for (int ci = 0; ci < 2; ++ci)
#pragma unroll
            for (int ks = 0; ks < 8; ++ks)
                b1r[ci][ks] = *(const bf16x8*)(
                    W1P + (long)((((c * 8 + w * 2 + ci) * 8 + ks) << 6) + l) * 8);

        f32x4 hacc[4][2];
#pragma unroll
        for (int i = 0; i < 4; ++i)
#pragma unroll
            for (int j = 0; j < 2; ++j) hacc[i][j] = (f32x4)(0.f);

#pragma unroll
        for (int ks = 0; ks < 8; ++ks) {
            bf16x8 a[4];
#pragma unroll
            for (int ri = 0; ri < 4; ++ri) {
                int r = ri * 16 + l15;
                int db = (r << 9) + ks * 64 + lh * 16;
                db ^= (r & 7) << 4;
                a[ri] = *(const bf16x8*)((const char*)Xs + db);
            }
#pragma unroll
            for (int ci = 0; ci < 2; ++ci)
#pragma unroll
                for (int ri = 0; ri < 4; ++ri)
                    hacc[ri][ci] = __builtin_amdgcn_mfma_f32_16x16x32_bf16(
                        a[ri], b1r[ci][ks], hacc[ri][ci], 0, 0, 0);
        }

        // -- phase 2 B fragments issued early (in flight across barrier) --
        bf16x8 b2r[4][4];
#pragma unroll
        for (int ci = 0; ci < 4; ++ci)
#pragma unroll
            for (int ks = 0; ks < 4; ++ks)
                b2r[ci][ks] = *(const bf16x8*)(
                    W2P + (long)((((w * 4 + ci) * 32 + c * 4 + ks) << 6) + l) * 8);

        // -- write H = relu(hacc + b1) --
        short* hb = Hs[c & 1];
#pragma unroll
        for (int ci = 0; ci < 2; ++ci) {
            float bias = b1[c * 128 + w * 32 + ci * 16 + l15];
            int colb = (w * 32 + ci * 16 + l15) * 2;
#pragma unroll
            for (int ri = 0; ri < 4; ++ri)
#pragma unroll
                for (int rg = 0; rg < 4; ++rg) {
                    int r = ri * 16 + lh * 4 + rg;
                    int db = (r << 8) + colb;
                    db ^= (r & 7) << 4;
                    *(__hip_bfloat16*)((char*)hb + db) =
                        __float2bfloat16(fmaxf(hacc[ri][ci][rg] + bias, 0.f));
                }
        }
        __syncthreads();

        // -- phase 2 --
#pragma unroll
        for (int ks = 0; ks < 4; ++ks) {
            bf16x8 a[4];
#pragma unroll
            for (int ri = 0; ri < 4; ++ri) {
                int r = ri * 16 + l15;
                int db = (r << 8) + ks * 64 + lh * 16;
                db ^= (r & 7) << 4;
                a[ri] = *(const bf16x8*)((const char*)hb + db);
            }
#pragma unroll
            for (int ci = 0; ci < 4; ++ci)
#pragma unroll
                for (int ri = 0; ri < 4; ++ri)
                    oacc[ri][ci] = __builtin_amdgcn_mfma_f32_16x16x32_bf16(
                        a[ri], b2r[ci][ks], oacc[ri][ci], 0, 0, 0);
        }
    }

    // -- epilogue: residual + LN2 --
    float b2c[4], g2c[4], be2c[4];
#pragma unroll
    for (int ci = 0; ci < 4; ++ci) {
        int n = w * 64 + ci * 16 + l15;
        b2c[ci] = b2[n]; g2c[ci] = g2[n]; be2c[ci] = be2[n];
    }
#pragma unroll
    for (int ri = 0; ri < 4; ++ri)
#pragma unroll
        for (int rg = 0; rg < 4; ++rg) {
            int r = ri * 16 + lh * 4 + rg;
            float s = 0.f, q = 0.f;
#pragma unroll
            for (int ci = 0; ci < 4; ++ci) {
                int db = (r << 9) + (w * 64 + ci * 16 + l15) * 2;
                db ^= (r & 7) << 4;
                float xn = __bfloat162float(*(__hip_bfloat16*)((char*)Xs + db));
                float v = oacc[ri][ci][rg] + xn + b2c[ci];
                oacc[ri][ci][rg] = v;
                s += v; q += v * v;
            }
#pragma unroll
            for (int o = 8; o > 0; o >>= 1) {
                s += __shfl_xor(s, o); q += __shfl_xor(q, o);
            }
            if (l15 == 0) { red[w][r][0] = s; red[w][r][1] = q; }
        }
    __syncthreads();
    if (t < 64) {
        float S = 0.f, Q = 0.f;
#pragma unroll
        for (int ww = 0; ww < 4; ++ww) { S += red[ww][t][0]; Q += red[ww][t][1]; }
        float mu = S * (1.f / CC);
        float var = Q * (1.f / CC) - mu * mu;
        mrs[t][0] = mu; mrs[t][1] = rsqrtf(var + EPSF);
    }
    __syncthreads();
#pragma unroll
    for (int ri = 0; ri < 4; ++ri)
#pragma unroll
        for (int rg = 0; rg < 4; ++rg) {
            int r = ri * 16 + lh * 4 + rg;
            float mu = mrs[r][0], rs = mrs[r][1];
#pragma unroll
            for (int ci = 0; ci < 4; ++ci) {
                int col = w * 64 + ci * 16 + l15;
                out[(long)(row0 + r) * CC + col] =
                    (oacc[ri][ci][rg] - mu) * rs * g2c[ci] + be2c[ci];
            }
        }
}

// ---------------------------------------------------------------------------
extern "C" void kernel_launch(void* const* d_in, const int* in_sizes, int n_in,
                              void* d_out, int out_size, void* d_ws, size_t ws_size,
                              hipStream_t stream) {
    const float* X   = (const float*)d_in[0];
    const int*   sel = (const int*)d_in[1];
    const float* pe  = (const float*)d_in[3];
    const float* Wq  = (const float*)d_in[4];
    const float* bq  = (const float*)d_in[5];
    const float* Wk  = (const float*)d_in[6];
    const float* bk  = (const float*)d_in[7];
    const float* Wv  = (const float*)d_in[8];
    const float* bv  = (const float*)d_in[9];
    const float* Wo  = (const float*)d_in[10];
    const float* bo  = (const float*)d_in[11];
    const float* W1  = (const float*)d_in[12];
    const float* b1  = (const float*)d_in[13];
    const float* W2  = (const float*)d_in[14];
    const float* b2  = (const float*)d_in[15];
    const float* g1  = (const float*)d_in[16];
    const float* be1 = (const float*)d_in[17];
    const float* g2  = (const float*)d_in[18];
    const float* be2 = (const float*)d_in[19];

    float* out = (float*)d_out;
    char*  ws  = (char*)d_ws;

    __hip_bfloat16* Xpb = (__hip_bfloat16*)(ws);                  // 16 MB
    __hip_bfloat16* Qb  = (__hip_bfloat16*)(ws + (16 << 20));     // 4 MB
    __hip_bfloat16* Kb  = (__hip_bfloat16*)(ws + (20 << 20));     // 4 MB
    __hip_bfloat16* Vb  = (__hip_bfloat16*)(ws + (24 << 20));     // 4 MB
    __hip_bfloat16* ctxb= (__hip_bfloat16*)(ws + (28 << 20));     // 4 MB
    __hip_bfloat16* Xnb = (__hip_bfloat16*)(ws + (32 << 20));     // 16 MB
    __hip_bfloat16* WqP = (__hip_bfloat16*)(ws + (48 << 20));     // 32 KB
    __hip_bfloat16* WkP = WqP + 16384;
    __hip_bfloat16* WvP = WkP + 16384;
    __hip_bfloat16* WoP = WvP + 16384;                            // 32 KB
    __hip_bfloat16* W1P = WoP + 16384;                            // 512 KB
    __hip_bfloat16* W2P = W1P + 262144;                           // 512 KB
    float* attn_out = out + (long)ROWS * CC;

    k_pack<<<64,   256, 0, stream>>>(Wq, WqP, CC, DD);
    k_pack<<<64,   256, 0, stream>>>(Wk, WkP, CC, DD);
    k_pack<<<64,   256, 0, stream>>>(Wv, WvP, CC, DD);
    k_pack<<<64,   256, 0, stream>>>(Wo, WoP, DD, CC);
    k_pack<<<1024, 256, 0, stream>>>(W1, W1P, CC, 4 * CC);
    k_pack<<<1024, 256, 0, stream>>>(W2, W2P, 4 * CC, CC);

    k_qkv<<<ROWS / 64, 256, 0, stream>>>((const float4*)X, (const float4*)pe,
                                         WqP, WkP, WvP, bq, bk, bv,
                                         Xpb, Qb, Kb, Vb);

    k_attn<<<ROWS / 4, 256, 0, stream>>>(Qb, Kb, Vb, sel, ctxb, attn_out);

    k_projln<<<ROWS / 64, 256, 0, stream>>>(ctxb, WoP, bo, g1, be1, Xpb, Xnb);

    k_ffn_mfma<<<ROWS / 64, 256, 0, stream>>>(Xnb, W1P, b1, W2P, b2, g2, be2, out);
}

// Round 4
// 149.862 us; speedup vs baseline: 6.6864x; 1.2632x over previous
//
#include <hip/hip_runtime.h>
#include <hip/hip_bf16.h>

#define CC 256
#define DD 64
#define PP 18
#define ROWS 32768
#define EPSF 1e-5f

typedef __attribute__((ext_vector_type(8))) short bf16x8;
typedef __attribute__((ext_vector_type(4))) short s16x4;
typedef __attribute__((ext_vector_type(4))) float f32x4;

// ---------------------------------------------------------------------------
// One fused pack kernel: fp32 W[K][N] (k-major) -> MFMA B-fragment order bf16:
// out[((nt*(K/32) + ks)*64 + l)*8 + e] = W[ks*32 + (l>>4)*8 + e][nt*16 + (l&15)]
// Segments: Wq,Wk,Wv (256x64), Wo (64x256), W1 (256x1024), W2 (1024x256).
__global__ __launch_bounds__(256) void k_pack_all(
    const float* __restrict__ Wq, const float* __restrict__ Wk,
    const float* __restrict__ Wv, const float* __restrict__ Wo,
    const float* __restrict__ W1, const float* __restrict__ W2,
    __hip_bfloat16* __restrict__ WqP, __hip_bfloat16* __restrict__ WkP,
    __hip_bfloat16* __restrict__ WvP, __hip_bfloat16* __restrict__ WoP,
    __hip_bfloat16* __restrict__ W1P, __hip_bfloat16* __restrict__ W2P) {
    int i = blockIdx.x * 256 + threadIdx.x;
    const float* src; __hip_bfloat16* dst; int K, N, j;
    if (i < 16384)       { src = Wq; dst = WqP; K = 256;  N = 64;   j = i; }
    else if (i < 32768)  { src = Wk; dst = WkP; K = 256;  N = 64;   j = i - 16384; }
    else if (i < 49152)  { src = Wv; dst = WvP; K = 256;  N = 64;   j = i - 32768; }
    else if (i < 65536)  { src = Wo; dst = WoP; K = 64;   N = 256;  j = i - 49152; }
    else if (i < 327680) { src = W1; dst = W1P; K = 256;  N = 1024; j = i - 65536; }
    else if (i < 589824) { src = W2; dst = W2P; K = 1024; N = 256;  j = i - 327680; }
    else return;
    int e = j & 7, l = (j >> 3) & 63, rest = j >> 9;
    int KS = K >> 5;
    int ks = rest % KS, nt = rest / KS;
    int row = ks * 32 + (l >> 4) * 8 + e;
    int col = nt * 16 + (l & 15);
    dst[j] = __float2bfloat16(src[(long)row * N + col]);
}

// ---------------------------------------------------------------------------
// Fused QKV. 32 rows/block (1024 blocks), 4 waves. Stage Xp=X+pe in LDS
// (swizzled bf16, also written to Xpb); hoist A-fragments to regs; wave w
// computes n-tiles {3w,3w+1,3w+2} of the 12 (Q:0-3,K:4-7,V:8-11) for both
// 16-row tiles.
__global__ __launch_bounds__(256) void k_qkv(
    const float4* __restrict__ X4, const float4* __restrict__ pe4,
    const __hip_bfloat16* __restrict__ WqP, const __hip_bfloat16* __restrict__ WkP,
    const __hip_bfloat16* __restrict__ WvP,
    const float* __restrict__ bq, const float* __restrict__ bk,
    const float* __restrict__ bv,
    __hip_bfloat16* __restrict__ Xpb,
    __hip_bfloat16* __restrict__ Qb, __hip_bfloat16* __restrict__ Kb,
    __hip_bfloat16* __restrict__ Vb) {
    __shared__ short Xs[32 * 256];      // 16 KB, swizzled
    const int t = threadIdx.x, w = t >> 6, l = t & 63;
    const int l15 = l & 15, lh = l >> 4;
    const int row0 = blockIdx.x * 32;

    for (int j = t; j < 2048; j += 256) {          // 32 rows x 64 float4
        int r = j >> 6, c4 = j & 63;
        long g = row0 + r;
        float4 a = X4[(g << 6) + c4];
        float4 p = pe4[(long)((g & 16383) << 6) + c4];
        union { s16x4 v; __hip_bfloat16 h[4]; } u;
        u.h[0] = __float2bfloat16(a.x + p.x);
        u.h[1] = __float2bfloat16(a.y + p.y);
        u.h[2] = __float2bfloat16(a.z + p.z);
        u.h[3] = __float2bfloat16(a.w + p.w);
        int db = (r << 9) + (c4 << 3);
        db ^= (r & 7) << 4;
        *(s16x4*)((char*)Xs + db) = u.v;
        *(s16x4*)((char*)Xpb + (g << 9) + (c4 << 3)) = u.v;
    }
    __syncthreads();

    // hoist A fragments: [ri][ks]
    bf16x8 af[2][8];
#pragma unroll
    for (int ri = 0; ri < 2; ++ri)
#pragma unroll
        for (int ks = 0; ks < 8; ++ks) {
            int r = ri * 16 + l15;
            int db = (r << 9) + ks * 64 + lh * 16;
            db ^= (r & 7) << 4;
            af[ri][ks] = *(const bf16x8*)((const char*)Xs + db);
        }

    f32x4 acc[3][2];
#pragma unroll
    for (int j = 0; j < 3; ++j)
#pragma unroll
        for (int ri = 0; ri < 2; ++ri) acc[j][ri] = (f32x4)(0.f);

#pragma unroll
    for (int ks = 0; ks < 8; ++ks)
#pragma unroll
        for (int j = 0; j < 3; ++j) {
            int nt = w * 3 + j;
            const __hip_bfloat16* WP = (nt < 4) ? WqP : ((nt < 8) ? WkP : WvP);
            int ntl = nt & 3;
            bf16x8 b = *(const bf16x8*)(WP + (long)(((ntl * 8 + ks) << 6) + l) * 8);
#pragma unroll
            for (int ri = 0; ri < 2; ++ri)
                acc[j][ri] = __builtin_amdgcn_mfma_f32_16x16x32_bf16(
                    af[ri][ks], b, acc[j][ri], 0, 0, 0);
        }

#pragma unroll
    for (int j = 0; j < 3; ++j) {
        int nt = w * 3 + j;
        __hip_bfloat16* OP = (nt < 4) ? Qb : ((nt < 8) ? Kb : Vb);
        const float* BP = (nt < 4) ? bq : ((nt < 8) ? bk : bv);
        int col = (nt & 3) * 16 + l15;
        float bias = BP[col];
#pragma unroll
        for (int ri = 0; ri < 2; ++ri)
#pragma unroll
            for (int rg = 0; rg < 4; ++rg) {
                long row = row0 + ri * 16 + lh * 4 + rg;
                OP[row * DD + col] = __float2bfloat16(acc[j][ri][rg] + bias);
            }
    }
}

// ---------------------------------------------------------------------------
// Gather-attention, bf16 K/V. One wave per token.
__global__ __launch_bounds__(256) void k_attn(const __hip_bfloat16* __restrict__ Q,
                                              const __hip_bfloat16* __restrict__ K,
                                              const __hip_bfloat16* __restrict__ V,
                                              const int* __restrict__ sel,
                                              __hip_bfloat16* __restrict__ ctx,
                                              float* __restrict__ attn_out) {
    const int wave  = threadIdx.x >> 6;
    const int lane  = threadIdx.x & 63;
    const int token = blockIdx.x * 4 + wave;
    const int b     = token >> 14;
    const float q   = __bfloat162float(Q[token * DD + lane]);

    int   idx[PP];
    float sc[PP];
    const int* selp = sel + (long)token * PP;
#pragma unroll
    for (int p = 0; p < PP; ++p) idx[p] = selp[p];

#pragma unroll
    for (int p = 0; p < PP; ++p) {
        float v = q * __bfloat162float(K[(((b << 14) + idx[p]) << 6) + lane]);
#pragma unroll
        for (int o = 32; o > 0; o >>= 1) v += __shfl_xor(v, o);
        sc[p] = v * 0.125f;
    }

    float mx = sc[0];
#pragma unroll
    for (int p = 1; p < PP; ++p) mx = fmaxf(mx, sc[p]);
    float e[PP];
    float s = 0.f;
#pragma unroll
    for (int p = 0; p < PP; ++p) { e[p] = expf(sc[p] - mx); s += e[p]; }
    const float inv = 1.f / s;

    float aval = 0.f;
#pragma unroll
    for (int p = 0; p < PP; ++p) aval = (lane == p) ? e[p] * inv : aval;
    if (lane < PP) attn_out[(long)token * PP + lane] = aval;

    float cv = 0.f;
#pragma unroll
    for (int p = 0; p < PP; ++p)
        cv += (e[p] * inv) * __bfloat162float(V[(((b << 14) + idx[p]) << 6) + lane]);
    ctx[token * DD + lane] = __float2bfloat16(cv);
}

// ---------------------------------------------------------------------------
// proj + LN1: Xn = LN(Xpb + ctx@Wo + bo)*g1 + be1 -> bf16.
// 32 rows/block (1024 blocks), 4 waves. Wave w: row-tile ri=w&1, col-half
// nh=w>>1 (8 n-tiles). Cross-wave LN over the 2 col-halves.
__global__ __launch_bounds__(256) void k_projln(
    const __hip_bfloat16* __restrict__ ctx, const __hip_bfloat16* __restrict__ WoP,
    const float* __restrict__ bo, const float* __restrict__ g1,
    const float* __restrict__ be1,
    const __hip_bfloat16* __restrict__ Xpb, __hip_bfloat16* __restrict__ Xnb) {
    __shared__ short Cs[32 * 64];       // 4 KB, swizzled
    __shared__ float red[2][32][2];
    __shared__ float mrs[32][2];
    const int t = threadIdx.x, w = t >> 6, l = t & 63;
    const int l15 = l & 15, lh = l >> 4;
    const int row0 = blockIdx.x * 32;

    {
        int r = t >> 3, ch = t & 7;                // 32 rows x 8 x 16B = 256
        int db = (r << 7) + (ch << 4);
        db ^= (r & 7) << 4;
        *(bf16x8*)((char*)Cs + db) = *(const bf16x8*)(ctx + (long)(row0 + r) * DD + ch * 8);
    }
    __syncthreads();

    const int ri = w & 1, nh = w >> 1;

    bf16x8 af[2];
#pragma unroll
    for (int ks = 0; ks < 2; ++ks) {
        int r = ri * 16 + l15;
        int db = (r << 7) + ks * 64 + lh * 16;
        db ^= (r & 7) << 4;
        af[ks] = *(const bf16x8*)((const char*)Cs + db);
    }

    f32x4 acc[8];
#pragma unroll
    for (int j = 0; j < 8; ++j) acc[j] = (f32x4)(0.f);

#pragma unroll
    for (int ks = 0; ks < 2; ++ks)
#pragma unroll
        for (int j = 0; j < 8; ++j) {
            int nt = nh * 8 + j;
            bf16x8 b = *(const bf16x8*)(WoP + (long)(((nt * 2 + ks) << 6) + l) * 8);
            acc[j] = __builtin_amdgcn_mfma_f32_16x16x32_bf16(af[ks], b, acc[j], 0, 0, 0);
        }

    float bov[8], g1v[8], be1v[8];
#pragma unroll
    for (int j = 0; j < 8; ++j) {
        int col = (nh * 8 + j) * 16 + l15;
        bov[j] = bo[col]; g1v[j] = g1[col]; be1v[j] = be1[col];
    }

    float xv[4][8];
#pragma unroll
    for (int rg = 0; rg < 4; ++rg) {
        long grow = row0 + ri * 16 + lh * 4 + rg;
        float s = 0.f, q = 0.f;
#pragma unroll
        for (int j = 0; j < 8; ++j) {
            float v = acc[j][rg] + bov[j] +
                      __bfloat162float(Xpb[grow * CC + (nh * 8 + j) * 16 + l15]);
            xv[rg][j] = v; s += v; q += v * v;
        }
#pragma unroll
        for (int o = 8; o > 0; o >>= 1) { s += __shfl_xor(s, o); q += __shfl_xor(q, o); }
        if (l15 == 0) {
            int rl = ri * 16 + lh * 4 + rg;
            red[nh][rl][0] = s; red[nh][rl][1] = q;
        }
    }
    __syncthreads();
    if (t < 32) {
        float S = red[0][t][0] + red[1][t][0];
        float Q = red[0][t][1] + red[1][t][1];
        float mu = S * (1.f / CC);
        float var = Q * (1.f / CC) - mu * mu;
        mrs[t][0] = mu; mrs[t][1] = rsqrtf(var + EPSF);
    }
    __syncthreads();
#pragma unroll
    for (int rg = 0; rg < 4; ++rg) {
        int rl = ri * 16 + lh * 4 + rg;
        long grow = row0 + rl;
        float mu = mrs[rl][0], rs = mrs[rl][1];
#pragma unroll
        for (int j = 0; j < 8; ++j)
            Xnb[grow * CC + (nh * 8 + j) * 16 + l15] =
                __float2bfloat16((xv[rg][j] - mu) * rs * g1v[j] + be1v[j]);
    }
}

// ---------------------------------------------------------------------------
// Fused FFN + LN2. 32 rows/block (1024 blocks), 4 waves, 8 hidden chunks of
// 128. A-fragments hoisted to regs (chunk-invariant); H double-buffered in
// LDS (1 barrier/chunk). ~34 KB LDS -> 4 blocks/CU, 16 waves/CU.
__global__ __launch_bounds__(256) void k_ffn_mfma(
    const __hip_bfloat16* __restrict__ Xn,
    const __hip_bfloat16* __restrict__ W1P, const float* __restrict__ b1,
    const __hip_bfloat16* __restrict__ W2P, const float* __restrict__ b2,
    const float* __restrict__ g2, const float* __restrict__ be2,
    float* __restrict__ out) {
    __shared__ short Xs[32 * 256];      // 16 KB
    __shared__ short Hs[2][32 * 128];   // 16 KB
    __shared__ float red[4][32][2];     // 1 KB
    __shared__ float mrs[32][2];

    const int t = threadIdx.x, w = t >> 6, l = t & 63;
    const int l15 = l & 15, lh = l >> 4;
    const int row0 = blockIdx.x * 32;

    {
        const char* src = (const char*)(Xn + (long)row0 * CC);
        for (int j = t; j < 1024; j += 256) {      // 32 rows x 32 x 16B
            int r = j >> 5;
            int db = (r << 9) + ((j & 31) << 4);
            db ^= (r & 7) << 4;
            *(bf16x8*)((char*)Xs + db) = *(const bf16x8*)(src + ((long)j << 4));
        }
    }
    __syncthreads();

    // hoist A fragments (chunk-invariant): [ri][ks]
    bf16x8 af[2][8];
#pragma unroll
    for (int ri = 0; ri < 2; ++ri)
#pragma unroll
        for (int ks = 0; ks < 8; ++ks) {
            int r = ri * 16 + l15;
            int db = (r << 9) + ks * 64 + lh * 16;
            db ^= (r & 7) << 4;
            af[ri][ks] = *(const bf16x8*)((const char*)Xs + db);
        }

    f32x4 oacc[2][4];
#pragma unroll
    for (int i = 0; i < 2; ++i)
#pragma unroll
        for (int j = 0; j < 4; ++j) oacc[i][j] = (f32x4)(0.f);

    for (int c = 0; c < 8; ++c) {
        // phase-1 B fragments (coalesced packed, L2-resident)
        bf16x8 b1r[2][8];
#pragma unroll
        for (int ci = 0; ci < 2; ++ci)
#pragma unroll
            for (int ks = 0; ks < 8; ++ks)
                b1r[ci][ks] = *(const bf16x8*)(
                    W1P + (long)((((c * 8 + w * 2 + ci) * 8 + ks) << 6) + l) * 8);

        f32x4 hacc[2][2];
#pragma unroll
        for (int i = 0; i < 2; ++i)
#pragma unroll
            for (int j = 0; j < 2; ++j) hacc[i][j] = (f32x4)(0.f);

#pragma unroll
        for (int ks = 0; ks < 8; ++ks)
#pragma unroll
            for (int ci = 0; ci < 2; ++ci)
#pragma unroll
                for (int ri = 0; ri < 2; ++ri)
                    hacc[ri][ci] = __builtin_amdgcn_mfma_f32_16x16x32_bf16(
                        af[ri][ks], b1r[ci][ks], hacc[ri][ci], 0, 0, 0);

        // phase-2 B fragments issued before the barrier (stay in flight)
        bf16x8 b2r[4][4];
#pragma unroll
        for (int ci = 0; ci < 4; ++ci)
#pragma unroll
            for (int ks = 0; ks < 4; ++ks)
                b2r[ci][ks] = *(const bf16x8*)(
                    W2P + (long)((((w * 4 + ci) * 32 + c * 4 + ks) << 6) + l) * 8);

        // write H = relu(hacc + b1) to LDS (bf16, swizzled)
        short* hb = Hs[c & 1];
#pragma unroll
        for (int ci = 0; ci < 2; ++ci) {
            float bias = b1[c * 128 + w * 32 + ci * 16 + l15];
            int colb = (w * 32 + ci * 16 + l15) * 2;
#pragma unroll
            for (int ri = 0; ri < 2; ++ri)
#pragma unroll
                for (int rg = 0; rg < 4; ++rg) {
                    int r = ri * 16 + lh * 4 + rg;
                    int db = (r << 8) + colb;
                    db ^= (r & 7) << 4;
                    *(__hip_bfloat16*)((char*)hb + db) =
                        __float2bfloat16(fmaxf(hacc[ri][ci][rg] + bias, 0.f));
                }
        }
        __syncthreads();

        // phase 2: oacc += H @ W2c
#pragma unroll
        for (int ks = 0; ks < 4; ++ks) {
            bf16x8 a[2];
#pragma unroll
            for (int ri = 0; ri < 2; ++ri) {
                int r = ri * 16 + l15;
                int db = (r << 8) + ks * 64 + lh * 16;
                db ^= (r & 7) << 4;
                a[ri] = *(const bf16x8*)((const char*)hb + db);
            }
#pragma unroll
            for (int ci = 0; ci < 4; ++ci)
#pragma unroll
                for (int ri = 0; ri < 2; ++ri)
                    oacc[ri][ci] = __builtin_amdgcn_mfma_f32_16x16x32_bf16(
                        a[ri], b2r[ci][ks], oacc[ri][ci], 0, 0, 0);
        }
    }

    // epilogue: residual + LN2
    float b2c[4], g2c[4], be2c[4];
#pragma unroll
    for (int ci = 0; ci < 4; ++ci) {
        int n = w * 64 + ci * 16 + l15;
        b2c[ci] = b2[n]; g2c[ci] = g2[n]; be2c[ci] = be2[n];
    }
#pragma unroll
    for (int ri = 0; ri < 2; ++ri)
#pragma unroll
        for (int rg = 0; rg < 4; ++rg) {
            int r = ri * 16 + lh * 4 + rg;
            float s = 0.f, q = 0.f;
#pragma unroll
            for (int ci = 0; ci < 4; ++ci) {
                int db = (r << 9) + (w * 64 + ci * 16 + l15) * 2;
                db ^= (r & 7) << 4;
                float xn = __bfloat162float(*(__hip_bfloat16*)((char*)Xs + db));
                float v = oacc[ri][ci][rg] + xn + b2c[ci];
                oacc[ri][ci][rg] = v;
                s += v; q += v * v;
            }
#pragma unroll
            for (int o = 8; o > 0; o >>= 1) {
                s += __shfl_xor(s, o); q += __shfl_xor(q, o);
            }
            if (l15 == 0) { red[w][r][0] = s; red[w][r][1] = q; }
        }
    __syncthreads();
    if (t < 32) {
        float S = 0.f, Q = 0.f;
#pragma unroll
        for (int ww = 0; ww < 4; ++ww) { S += red[ww][t][0]; Q += red[ww][t][1]; }
        float mu = S * (1.f / CC);
        float var = Q * (1.f / CC) - mu * mu;
        mrs[t][0] = mu; mrs[t][1] = rsqrtf(var + EPSF);
    }
    __syncthreads();
#pragma unroll
    for (int ri = 0; ri < 2; ++ri)
#pragma unroll
        for (int rg = 0; rg < 4; ++rg) {
            int r = ri * 16 + lh * 4 + rg;
            float mu = mrs[r][0], rs = mrs[r][1];
#pragma unroll
            for (int ci = 0; ci < 4; ++ci) {
                int col = w * 64 + ci * 16 + l15;
                out[(long)(row0 + r) * CC + col] =
                    (oacc[ri][ci][rg] - mu) * rs * g2c[ci] + be2c[ci];
            }
        }
}

// ---------------------------------------------------------------------------
extern "C" void kernel_launch(void* const* d_in, const int* in_sizes, int n_in,
                              void* d_out, int out_size, void* d_ws, size_t ws_size,
                              hipStream_t stream) {
    const float* X   = (const float*)d_in[0];
    const int*   sel = (const int*)d_in[1];
    const float* pe  = (const float*)d_in[3];
    const float* Wq  = (const float*)d_in[4];
    const float* bq  = (const float*)d_in[5];
    const float* Wk  = (const float*)d_in[6];
    const float* bk  = (const float*)d_in[7];
    const float* Wv  = (const float*)d_in[8];
    const float* bv  = (const float*)d_in[9];
    const float* Wo  = (const float*)d_in[10];
    const float* bo  = (const float*)d_in[11];
    const float* W1  = (const float*)d_in[12];
    const float* b1  = (const float*)d_in[13];
    const float* W2  = (const float*)d_in[14];
    const float* b2  = (const float*)d_in[15];
    const float* g1  = (const float*)d_in[16];
    const float* be1 = (const float*)d_in[17];
    const float* g2  = (const float*)d_in[18];
    const float* be2 = (const float*)d_in[19];

    float* out = (float*)d_out;
    char*  ws  = (char*)d_ws;

    __hip_bfloat16* Xpb = (__hip_bfloat16*)(ws);                  // 16 MB
    __hip_bfloat16* Qb  = (__hip_bfloat16*)(ws + (16 << 20));     // 4 MB
    __hip_bfloat16* Kb  = (__hip_bfloat16*)(ws + (20 << 20));     // 4 MB
    __hip_bfloat16* Vb  = (__hip_bfloat16*)(ws + (24 << 20));     // 4 MB
    __hip_bfloat16* ctxb= (__hip_bfloat16*)(ws + (28 << 20));     // 4 MB
    __hip_bfloat16* Xnb = (__hip_bfloat16*)(ws + (32 << 20));     // 16 MB
    __hip_bfloat16* WqP = (__hip_bfloat16*)(ws + (48 << 20));     // 32 KB
    __hip_bfloat16* WkP = WqP + 16384;
    __hip_bfloat16* WvP = WkP + 16384;
    __hip_bfloat16* WoP = WvP + 16384;                            // 32 KB
    __hip_bfloat16* W1P = WoP + 16384;                            // 512 KB
    __hip_bfloat16* W2P = W1P + 262144;                           // 512 KB
    float* attn_out = out + (long)ROWS * CC;

    k_pack_all<<<2304, 256, 0, stream>>>(Wq, Wk, Wv, Wo, W1, W2,
                                         WqP, WkP, WvP, WoP, W1P, W2P);

    k_qkv<<<ROWS / 32, 256, 0, stream>>>((const float4*)X, (const float4*)pe,
                                         WqP, WkP, WvP, bq, bk, bv,
                                         Xpb, Qb, Kb, Vb);

    k_attn<<<ROWS / 4, 256, 0, stream>>>(Qb, Kb, Vb, sel, ctxb, attn_out);

    k_projln<<<ROWS / 32, 256, 0, stream>>>(ctxb, WoP, bo, g1, be1, Xpb, Xnb);

    k_ffn_mfma<<<ROWS / 32, 256, 0, stream>>>(Xnb, W1P, b1, W2P, b2, g2, be2, out);
}